// Round 2
// baseline (411.767 us; speedup 1.0000x reference)
//
#include <hip/hip_runtime.h>
#include <hip/hip_bf16.h>

// Problem constants
constexpr int BB   = 16;
constexpr int TT_  = 392;          // T
constexpr int CC   = 512;          // C (= E)
constexpr int E8_  = 64;           // E/8
constexpr int KK   = 196;          // top_k
constexpr long TT2 = 153664;       // T*T
constexpr long OUT_HALF = 1229312; // B*T*K

// k_xt tiling: per-wave 16b x 16j tile, K = 1568 per c-chunk in 49 steps of 32.
constexpr int NC2 = 98;            // K-chunks (c)
constexpr int CH2 = 1568;          // K per chunk (NC2*CH2 = T*T)
constexpr int NJT16 = 25;          // j-tiles of 16 (25*16 = 400 >= 392)
// grid: 8 XCD groups x 13 c-slots x 7 jt4-blocks = 728 blocks of 4 waves.
// wg%8 == c%8 pins all 7 blocks (25 j-tile waves) of a chunk to one XCD ->
// its 50 KB att slice is HBM-fetched once, L2-served after.

// k_att LDS stride (rows 8-mod-16 aligned: dword-stride 2 mod 4 -> 2-way free)
constexpr int LDA = 68;

typedef __bf16 bf16_t;
typedef bf16_t bf16x8 __attribute__((ext_vector_type(8)));
typedef float  f32x4  __attribute__((ext_vector_type(4)));

static __device__ __forceinline__ unsigned int pk2(float a, float b) {
    unsigned short lo = __builtin_bit_cast(unsigned short, (bf16_t)a);
    unsigned short hi = __builtin_bit_cast(unsigned short, (bf16_t)b);
    return ((unsigned int)hi << 16) | (unsigned int)lo;
}
static __device__ __forceinline__ bf16x8 cvt8(f32x4 a, f32x4 b) {
    uint4 u = make_uint4(pk2(a.x, a.y), pk2(a.z, a.w), pk2(b.x, b.y), pk2(b.z, b.w));
    return __builtin_bit_cast(bf16x8, u);
}
// 8B-aligned LDS fragment load (k_att)
static __device__ __forceinline__ bf16x8 ld_frag(const bf16_t* p) {
    uint2 lo = *(const uint2*)p;
    uint2 hi = *(const uint2*)(p + 4);
    uint4 u = make_uint4(lo.x, lo.y, hi.x, hi.y);
    return __builtin_bit_cast(bf16x8, u);
}

// ---------------------------------------------------------------- xi = bf16(x @ W_dim^T + b_dim)
// LDS-free: every x row feeds one wave; W_dim (131 KB) is L2-hot across the 98 blocks.
// Per wave: 16 m-rows x 64 e, K=512 in 16 steps, 2-deep register pipeline.
// Also zero-inits xt (ws is poisoned every call).
__global__ __launch_bounds__(256) void k_xi(const float* __restrict__ x,
                                            const float* __restrict__ Wd,
                                            const float* __restrict__ bd,
                                            unsigned short* __restrict__ xi_b,
                                            float* __restrict__ xt) {
    int tid = threadIdx.x;
    if (blockIdx.x < 25) {
        int o = blockIdx.x * 256 + tid;
        if (o < BB * TT_) xt[o] = 0.f;
    }
    int wv = tid >> 6, lane = tid & 63;
    int n = lane & 15, quad = lane >> 4;
    int m = blockIdx.x * 64 + wv * 16 + n;          // 98*64 = 6272 = B*T exactly
    const float* xp = x  + (size_t)m * CC + quad * 8;
    const float* wp = Wd + (size_t)n * CC + quad * 8;   // + nt*16*CC for e-row

    f32x4 acc[4] = {};
    f32x4 a0c, a1c, b0c[4], b1c[4];
    a0c = *(const f32x4*)xp;
    a1c = *(const f32x4*)(xp + 4);
    #pragma unroll
    for (int nt = 0; nt < 4; ++nt) {
        b0c[nt] = *(const f32x4*)(wp + (size_t)nt * 16 * CC);
        b1c[nt] = *(const f32x4*)(wp + (size_t)nt * 16 * CC + 4);
    }
    for (int kt = 0; kt < 16; ++kt) {
        f32x4 a0n, a1n, b0n[4], b1n[4];
        if (kt < 15) {
            a0n = *(const f32x4*)(xp + (kt + 1) * 32);
            a1n = *(const f32x4*)(xp + (kt + 1) * 32 + 4);
            #pragma unroll
            for (int nt = 0; nt < 4; ++nt) {
                b0n[nt] = *(const f32x4*)(wp + (size_t)nt * 16 * CC + (kt + 1) * 32);
                b1n[nt] = *(const f32x4*)(wp + (size_t)nt * 16 * CC + (kt + 1) * 32 + 4);
            }
        }
        bf16x8 a = cvt8(a0c, a1c);
        #pragma unroll
        for (int nt = 0; nt < 4; ++nt) {
            bf16x8 b = cvt8(b0c[nt], b1c[nt]);
            acc[nt] = __builtin_amdgcn_mfma_f32_16x16x32_bf16(a, b, acc[nt], 0, 0, 0);
        }
        if (kt < 15) {
            a0c = a0n; a1c = a1n;
            #pragma unroll
            for (int nt = 0; nt < 4; ++nt) { b0c[nt] = b0n[nt]; b1c[nt] = b1n[nt]; }
        }
    }
    #pragma unroll
    for (int nt = 0; nt < 4; ++nt)
        #pragma unroll
        for (int r = 0; r < 4; ++r) {
            int mm = blockIdx.x * 64 + wv * 16 + quad * 4 + r;
            int e = nt * 16 + n;
            xi_b[(size_t)mm * E8_ + e] =
                __builtin_bit_cast(unsigned short, (bf16_t)(acc[nt][r] + bd[e]));
        }
}

// ---------------------------------------------------------------- fused scores + softmax -> att bf16
// grid (16 b, 7 ti-tiles), block 256 (4 waves). Wave: 16 ti x full 392 tj (25 n-tiles).
// Same-b blocks are 16 apart in linear id -> same XCD (xi slice stays L2-hot).
__global__ __launch_bounds__(256) void k_att(const unsigned short* __restrict__ xi_b,
                                             unsigned short* __restrict__ att_b) {
    __shared__ bf16_t Xb[400 * LDA];
    int b = blockIdx.x, tb = blockIdx.y;
    int tid = threadIdx.x;
    int wv = tid >> 6, lane = tid & 63;
    int n = lane & 15, quad = lane >> 4;
    #pragma unroll
    for (int t = 0; t < 13; ++t) {
        int s = t * 256 + tid;              // 0..3327, guard 3200
        if (s < 3200) {
            int r = s >> 3, c8 = s & 7;
            uint2 lo = make_uint2(0u, 0u), hi = make_uint2(0u, 0u);
            if (r < TT_) {
                uint4 v = *(const uint4*)(xi_b + ((size_t)(b * TT_ + r)) * E8_ + c8 * 8);
                lo = make_uint2(v.x, v.y);
                hi = make_uint2(v.z, v.w);
            }
            *(uint2*)(&Xb[r * LDA + c8 * 8])     = lo;
            *(uint2*)(&Xb[r * LDA + c8 * 8 + 4]) = hi;
        }
    }
    __syncthreads();
    int arow = tb * 64 + wv * 16 + n;
    if (arow > 399) arow = 399;
    bf16x8 a0 = ld_frag(&Xb[arow * LDA + quad * 8]);
    bf16x8 a1 = ld_frag(&Xb[arow * LDA + 32 + quad * 8]);
    f32x4 acc[25];
    #pragma unroll
    for (int nt = 0; nt < 25; ++nt) acc[nt] = (f32x4){0.f, 0.f, 0.f, 0.f};
    #pragma unroll
    for (int nt = 0; nt < 25; ++nt) {
        bf16x8 b0 = ld_frag(&Xb[(nt * 16 + n) * LDA + quad * 8]);
        bf16x8 b1 = ld_frag(&Xb[(nt * 16 + n) * LDA + 32 + quad * 8]);
        acc[nt] = __builtin_amdgcn_mfma_f32_16x16x32_bf16(a0, b0, acc[nt], 0, 0, 0);
        acc[nt] = __builtin_amdgcn_mfma_f32_16x16x32_bf16(a1, b1, acc[nt], 0, 0, 0);
    }
    const float scaler = 1.0f / 512.0f;
    float mx[4] = {-1e30f, -1e30f, -1e30f, -1e30f};
    #pragma unroll
    for (int nt = 0; nt < 25; ++nt) {
        bool valid = (nt * 16 + n) < TT_;
        #pragma unroll
        for (int r = 0; r < 4; ++r) {
            float v = valid ? acc[nt][r] * scaler : -1e30f;
            acc[nt][r] = v;
            mx[r] = fmaxf(mx[r], v);
        }
    }
    #pragma unroll
    for (int r = 0; r < 4; ++r) {
        #pragma unroll
        for (int o = 1; o < 16; o <<= 1) mx[r] = fmaxf(mx[r], __shfl_xor(mx[r], o, 64));
    }
    float sm[4] = {0.f, 0.f, 0.f, 0.f};
    #pragma unroll
    for (int nt = 0; nt < 25; ++nt)
        #pragma unroll
        for (int r = 0; r < 4; ++r) {
            float e = __expf(acc[nt][r] - mx[r]);
            acc[nt][r] = e;
            sm[r] += e;
        }
    #pragma unroll
    for (int r = 0; r < 4; ++r) {
        #pragma unroll
        for (int o = 1; o < 16; o <<= 1) sm[r] += __shfl_xor(sm[r], o, 64);
        sm[r] = 1.0f / sm[r];
    }
    unsigned short* dst = att_b + (size_t)b * TT2;
    #pragma unroll
    for (int r = 0; r < 4; ++r) {
        int ti = tb * 64 + wv * 16 + quad * 4 + r;
        if (ti < TT_) {
            #pragma unroll
            for (int nt = 0; nt < 25; ++nt) {
                int tj = nt * 16 + n;
                if (tj < TT_)
                    dst[(size_t)ti * TT_ + tj] =
                        __builtin_bit_cast(unsigned short, (bf16_t)(acc[nt][r] * sm[r]));
            }
        }
    }
}

// ---------------------------------------------------------------- xt via MFMA + fp32 atomic accumulate
// LDS-free streaming: every W_time element feeds exactly one lane, so no sharing exists ->
// per-lane direct global loads (A: 16B bf16 att; B: 2x f32x4 W, 16 rows x 128B coalesced),
// 2-deep register pipeline, no barriers. XCD-pinned c-groups keep the att slice L2-resident.
__global__ __launch_bounds__(256) void k_xt(const float* __restrict__ Wt,
                                            const unsigned short* __restrict__ att_b,
                                            float* __restrict__ xt) {
    int wg = blockIdx.x;                    // 728 = 8 xcd * 13 cidx * 7 jt4
    int xcd = wg & 7, s = wg >> 3;          // s = 0..90
    int cidx = s / 7, jt4 = s - cidx * 7;
    int c = cidx * 8 + xcd;
    if (c >= NC2) return;                   // 42 idle blocks
    int tid = threadIdx.x;
    int wv = tid >> 6, lane = tid & 63;
    int n = lane & 15, quad = lane >> 4;
    int jt = jt4 * 4 + wv;
    if (jt >= NJT16) return;                // 3 idle waves on jt4 == 6
    int j = jt * 16 + n;
    int jl = j < TT_ ? j : TT_ - 1;         // clamp W row (store guarded)
    long kbase = (long)c * CH2;
    const unsigned short* ap = att_b + (size_t)n * TT2 + kbase + quad * 8;
    const float*          wp = Wt + (size_t)jl * TT2 + kbase + quad * 8;

    f32x4 acc = {0.f, 0.f, 0.f, 0.f};
    uint4 ac; f32x4 w0c, w1c;
    ac  = *(const uint4*)ap;
    w0c = *(const f32x4*)wp;
    w1c = *(const f32x4*)(wp + 4);
    for (int m = 0; m < 49; ++m) {          // K = 49 * 32, same order as before
        uint4 an; f32x4 w0n, w1n;
        if (m < 48) {
            ac.w = ac.w;                    // keep ac live
            an  = *(const uint4*)(ap + (m + 1) * 32);
            w0n = *(const f32x4*)(wp + (m + 1) * 32);
            w1n = *(const f32x4*)(wp + (m + 1) * 32 + 4);
        }
        bf16x8 a = __builtin_bit_cast(bf16x8, ac);
        bf16x8 b = cvt8(w0c, w1c);
        acc = __builtin_amdgcn_mfma_f32_16x16x32_bf16(a, b, acc, 0, 0, 0);
        if (m < 48) { ac = an; w0c = w0n; w1c = w1n; }
    }
    if (j < TT_) {
        #pragma unroll
        for (int r = 0; r < 4; ++r)
            unsafeAtomicAdd(&xt[(size_t)(quad * 4 + r) * TT_ + j], acc[r]);
    }
}

// ---------------------------------------------------------------- offsets -> unnormalized sample coord ix
__global__ __launch_bounds__(256) void k_off(const float* __restrict__ xt,
                                             const float* __restrict__ bt,
                                             const float* __restrict__ Wa,
                                             const float* __restrict__ Wd,
                                             float* __restrict__ wix) {
    int o = blockIdx.x * 256 + threadIdx.x;
    if (o >= 2 * BB * KK) return;                  // 6272
    int which = o / (BB * KK);                     // 0 = a, 1 = d
    int rem = o - which * (BB * KK);
    int b = rem / KK;
    int k = rem - b * KK;
    const f32x4* __restrict__ wr = (const f32x4*)((which ? Wd : Wa) + (size_t)k * TT_);
    const f32x4* __restrict__ xr = (const f32x4*)(xt + (size_t)b * TT_);
    const f32x4* __restrict__ br = (const f32x4*)bt;
    float acc = 0.f;
    #pragma unroll 2
    for (int q = 0; q < TT_ / 4; ++q) {
        f32x4 w = wr[q], x = xr[q], bb = br[q];
        acc += (x.x + bb.x) * w.x + (x.y + bb.y) * w.y
             + (x.z + bb.z) * w.z + (x.w + bb.w) * w.w;
    }
    float off = tanhf(acc) * 2.0f;                 // * RECEPTIVE_FIELD
    float idx = (float)(2 * k + which) + off;      // arange(0,t,2) or arange(1,t+1,2)
    float g = 2.0f * idx / 391.0f - 1.0f;          // normalize_grid, denom = t-1
    float ix = ((g + 1.0f) * 512.0f - 1.0f) * 0.5f; // grid_sample unnormalize, c=512
    wix[o] = ix;
}

// ---------------------------------------------------------------- bilinear gather along channels
__global__ __launch_bounds__(256) void k_sample(const float* __restrict__ x,
                                                const float* __restrict__ wix,
                                                float* __restrict__ out) {
    __shared__ float xr[4][512];
    int b = blockIdx.x, t0 = blockIdx.y * 4;
    int tid = threadIdx.x;
    const float* src = x + ((size_t)b * TT_ + t0) * CC;
    #pragma unroll
    for (int s = 0; s < 2; ++s) {
        int idx = s * 256 + tid;                   // 0..511 float4 slots
        ((f32x4*)xr)[idx] = ((const f32x4*)src)[idx];
    }
    __syncthreads();
    for (int w = tid; w < 2 * 4 * KK; w += 256) {  // 1568 items
        int which = (w >= 4 * KK) ? 1 : 0;
        int rem = w - which * 4 * KK;
        int tl = rem / KK;
        int k = rem - tl * KK;
        float ix = wix[(size_t)which * (BB * KK) + b * KK + k];
        float x0f = floorf(ix);
        float w1 = ix - x0f;
        int c0 = (int)x0f;
        int c1 = c0 + 1;
        c0 = min(max(c0, 0), CC - 1);
        c1 = min(max(c1, 0), CC - 1);
        float v0 = xr[tl][c0], v1 = xr[tl][c1];
        out[(size_t)which * OUT_HALF + ((size_t)(b * TT_) + t0 + tl) * KK + k] =
            v0 * (1.0f - w1) + v1 * w1;
    }
}

extern "C" void kernel_launch(void* const* d_in, const int* in_sizes, int n_in,
                              void* d_out, int out_size, void* d_ws, size_t ws_size,
                              hipStream_t stream) {
    const float* x_in   = (const float*)d_in[0];
    const float* W_dim  = (const float*)d_in[1];
    const float* b_dim  = (const float*)d_in[2];
    const float* W_time = (const float*)d_in[3];
    const float* b_time = (const float*)d_in[4];
    const float* W_offa = (const float*)d_in[5];
    const float* W_offd = (const float*)d_in[6];
    float* out = (float*)d_out;
    float* ws  = (float*)d_ws;

    // ws layout (float units):
    unsigned short* att_b = (unsigned short*)ws;             // 16*153664 bf16
    unsigned short* xi_b  = (unsigned short*)(ws + 1229312); // 6272*64 bf16
    float*          xt    = ws + 1630720;                    // 6,272 fl (zeroed by k_xi)
    float*          wix   = ws + 1636992;                    // 6,272 fl

    k_xi<<<98, 256, 0, stream>>>(x_in, W_dim, b_dim, xi_b, xt);
    k_att<<<dim3(BB, 7), 256, 0, stream>>>(xi_b, att_b);
    k_xt<<<728, 256, 0, stream>>>(W_time, att_b, xt);
    k_off<<<25, 256, 0, stream>>>(xt, b_time, W_offa, W_offd, wix);
    k_sample<<<dim3(BB, TT_ / 4), 256, 0, stream>>>(x_in, wix, out);
}